// Round 1
// 866.401 us; speedup vs baseline: 1.0243x; 1.0243x over previous
//
#include <hip/hip_runtime.h>
#include <hip/hip_bf16.h>

#define B_  16
#define TQ_ 1024
#define TK_ 4096
#define D_  512

typedef unsigned short u16;
typedef __attribute__((ext_vector_type(8))) short short8;      // 8 bf16
typedef __attribute__((ext_vector_type(8))) _Float16 f16x8;    // 8 f16 (4 VGPRs)
typedef __attribute__((ext_vector_type(4))) float f32x4;

__device__ __forceinline__ u16 bf16_rne(float x) {
  unsigned u = __float_as_uint(x);
  u += 0x7FFFu + ((u >> 16) & 1u);
  return (u16)(u >> 16);
}
__device__ __forceinline__ float bf16_as_f32(u16 h) {
  return __uint_as_float(((unsigned)h) << 16);
}
__device__ __forceinline__ void split_bf16(float x, u16& h, u16& l) {
  u16 hh = bf16_rne(x);
  h = hh;
  l = bf16_rne(x - bf16_as_f32(hh));
}

// async global->LDS, 16B per lane; LDS dest must be wave-contiguous (base + lane*16)
__device__ __forceinline__ void glld16(const void* g, void* lds) {
  __builtin_amdgcn_global_load_lds(
      (const __attribute__((address_space(1))) unsigned int*)g,
      (__attribute__((address_space(3))) unsigned int*)lds, 16, 0, 0);
}

// Conflict-free swizzle for [R][32]-f16 tiles staged via glld (linear LDS dest):
// LDS slot (row, s) holds global segment q = s ^ (row&3) ^ ((row>>2)&3).
// Staging: lane l of chunk c (row = 16c + (l>>2)) fetches global segment
//   q_src(l) = (l&3) ^ ((l>>2)&3) ^ ((l>>4)&3)   (chunk-independent).
// Reads: fragment (ln, qd) reads slot s = qd ^ (ln&3) ^ (ln>>2).
// Every aligned 16-lane group then covers all 8 LDS bank-groups exactly 2x (free).
__device__ __forceinline__ int seg_src(int l) {
  return (l & 3) ^ ((l >> 2) & 3) ^ ((l >> 4) & 3);
}

// ---------------------------------------------------------------------------
// enc [b][k][d] fp32 -> encT [b][d][k] f16  (+ optional encF16 [b][k][d] f16)
// ---------------------------------------------------------------------------
__global__ __launch_bounds__(256) void transpose_conv_kernel(
    const float* __restrict__ E, _Float16* __restrict__ ET,
    _Float16* __restrict__ EF)
{
  __shared__ float tile[64][65];
  const int b  = blockIdx.z;
  const int k0 = blockIdx.x * 64;
  const int d0 = blockIdx.y * 64;
  const float* Eb = E + (long long)b * TK_ * D_;
  _Float16* ETb = ET + (long long)b * D_ * TK_;

  const int t  = threadIdx.x;
  const int r  = t >> 2;          // 0..63
  const int c4 = (t & 3) * 16;    // 0,16,32,48

  __align__(16) _Float16 g[16];
  #pragma unroll
  for (int i = 0; i < 16; i += 4) {
    float4 v = *(const float4*)&Eb[(long long)(k0 + r) * D_ + d0 + c4 + i];
    tile[r][c4 + i + 0] = v.x;
    tile[r][c4 + i + 1] = v.y;
    tile[r][c4 + i + 2] = v.z;
    tile[r][c4 + i + 3] = v.w;
    g[i + 0] = (_Float16)v.x;
    g[i + 1] = (_Float16)v.y;
    g[i + 2] = (_Float16)v.z;
    g[i + 3] = (_Float16)v.w;
  }
  if (EF) {
    _Float16* EFb = EF + (long long)b * TK_ * D_;
    uint4* dstF = (uint4*)&EFb[(long long)(k0 + r) * D_ + d0 + c4];
    dstF[0] = ((const uint4*)g)[0];
    dstF[1] = ((const uint4*)g)[1];
  }
  __syncthreads();

  __align__(16) _Float16 h[16];
  #pragma unroll
  for (int i = 0; i < 16; ++i) h[i] = (_Float16)tile[c4 + i][r];
  uint4* dst = (uint4*)&ETb[(long long)(d0 + r) * TK_ + k0 + c4];
  dst[0] = ((const uint4*)h)[0];
  dst[1] = ((const uint4*)h)[1];
}

// ---------------------------------------------------------------------------
// dec2 = dec @ W^T  (split-bf16 triple, R1-proven), epilogue emits f16 hi/lo
// ---------------------------------------------------------------------------
#define DBM 128
#define DBN 128
#define DBK 32
#define DPAD 40

__global__ __launch_bounds__(256) void gemm_dec2_kernel(
    const float* __restrict__ A, const float* __restrict__ Bm,
    _Float16* __restrict__ Ch, _Float16* __restrict__ Cl)
{
  __shared__ u16 Ah[DBM * DPAD];
  __shared__ u16 Al[DBM * DPAD];
  __shared__ u16 Bh[DBN * DPAD];
  __shared__ u16 Bl[DBN * DPAD];

  const float* Ab = A  + (long long)(blockIdx.y * DBM) * D_;
  const float* Bb = Bm + (long long)(blockIdx.x * DBN) * D_;

  const int t    = threadIdx.x;
  const int r    = t >> 1;
  const int hf   = t & 1;
  const int lane = t & 63;
  const int wave = t >> 6;
  const int wr   = (wave >> 1) * 64;
  const int wc   = (wave & 1) * 64;
  const int ln   = lane & 15;
  const int qd   = lane >> 4;

  f32x4 acc[4][4];
  #pragma unroll
  for (int i = 0; i < 4; ++i)
    #pragma unroll
    for (int j = 0; j < 4; ++j) { f32x4 z = {0.f,0.f,0.f,0.f}; acc[i][j] = z; }

  const float* srcA = Ab + (long long)r * D_ + hf * 16;
  const float* srcB = Bb + (long long)r * D_ + hf * 16;
  u16* dAh = &Ah[r * DPAD + hf * 16];
  u16* dAl = &Al[r * DPAD + hf * 16];
  u16* dBh = &Bh[r * DPAD + hf * 16];
  u16* dBl = &Bl[r * DPAD + hf * 16];

  for (int k0 = 0; k0 < D_; k0 += DBK) {
    {
      __align__(16) u16 h[16], l[16];
      #pragma unroll
      for (int i = 0; i < 16; i += 4) {
        float4 v = *(const float4*)(srcA + k0 + i);
        split_bf16(v.x, h[i+0], l[i+0]);
        split_bf16(v.y, h[i+1], l[i+1]);
        split_bf16(v.z, h[i+2], l[i+2]);
        split_bf16(v.w, h[i+3], l[i+3]);
      }
      ((uint4*)dAh)[0] = ((const uint4*)h)[0];
      ((uint4*)dAh)[1] = ((const uint4*)h)[1];
      ((uint4*)dAl)[0] = ((const uint4*)l)[0];
      ((uint4*)dAl)[1] = ((const uint4*)l)[1];
      #pragma unroll
      for (int i = 0; i < 16; i += 4) {
        float4 v = *(const float4*)(srcB + k0 + i);
        split_bf16(v.x, h[i+0], l[i+0]);
        split_bf16(v.y, h[i+1], l[i+1]);
        split_bf16(v.z, h[i+2], l[i+2]);
        split_bf16(v.w, h[i+3], l[i+3]);
      }
      ((uint4*)dBh)[0] = ((const uint4*)h)[0];
      ((uint4*)dBh)[1] = ((const uint4*)h)[1];
      ((uint4*)dBl)[0] = ((const uint4*)l)[0];
      ((uint4*)dBl)[1] = ((const uint4*)l)[1];
    }
    __syncthreads();

    short8 fah[4], fal[4], fbh[4], fbl[4];
    #pragma unroll
    for (int i = 0; i < 4; ++i) {
      int ra = (wr + i * 16 + ln) * DPAD + qd * 8;
      int rb = (wc + i * 16 + ln) * DPAD + qd * 8;
      fah[i] = *(const short8*)&Ah[ra];
      fal[i] = *(const short8*)&Al[ra];
      fbh[i] = *(const short8*)&Bh[rb];
      fbl[i] = *(const short8*)&Bl[rb];
    }
    #pragma unroll
    for (int i = 0; i < 4; ++i)
      #pragma unroll
      for (int j = 0; j < 4; ++j) {
        acc[i][j] = __builtin_amdgcn_mfma_f32_16x16x32_bf16(fah[i], fbh[j], acc[i][j], 0, 0, 0);
        acc[i][j] = __builtin_amdgcn_mfma_f32_16x16x32_bf16(fah[i], fbl[j], acc[i][j], 0, 0, 0);
        acc[i][j] = __builtin_amdgcn_mfma_f32_16x16x32_bf16(fal[i], fbh[j], acc[i][j], 0, 0, 0);
      }
    __syncthreads();
  }

  const int m0 = blockIdx.y * DBM;
  const int n0 = blockIdx.x * DBN;
  #pragma unroll
  for (int i = 0; i < 4; ++i)
    #pragma unroll
    for (int j = 0; j < 4; ++j)
      #pragma unroll
      for (int rg = 0; rg < 4; ++rg) {
        int row = m0 + wr + i * 16 + qd * 4 + rg;
        int col = n0 + wc + j * 16 + ln;
        float x = acc[i][j][rg];
        _Float16 h = (_Float16)x;
        _Float16 l = (_Float16)(x - (float)h);
        long long idx = (long long)row * D_ + col;
        Ch[idx] = h;
        Cl[idx] = l;
      }
}

// ---------------------------------------------------------------------------
// Score GEMM: C[b][q][k] = sum_d dec2[b,q,d] * enc[b,k,d]
// A planes via glld (swizzled source), B: glld from encF16 (fast) or in-loop
// cvt of fp32 enc (fallback). LDS tiles XOR-swizzled -> conflict-free reads.
// ---------------------------------------------------------------------------
#define SBM 128
#define SBN 128
#define SBK 32

template<bool F16B>
__global__ __launch_bounds__(256) void gemm_score_kernel(
    const _Float16* __restrict__ A_h, const _Float16* __restrict__ A_l,
    const float* __restrict__ Bf, const _Float16* __restrict__ B16,
    float* __restrict__ C)
{
  __shared__ _Float16 sAh[SBM * SBK];   // 8 KB, glld-staged, swizzled layout
  __shared__ _Float16 sAl[SBM * SBK];   // 8 KB
  __shared__ _Float16 sB [SBN * SBK];   // 8 KB

  const int bz = blockIdx.z;
  const int m0 = blockIdx.y * SBM;
  const int n0 = blockIdx.x * SBN;
  const _Float16* Ahb = A_h + (long long)bz * TQ_ * D_ + (long long)m0 * D_;
  const _Float16* Alb = A_l + (long long)bz * TQ_ * D_ + (long long)m0 * D_;

  const int t    = threadIdx.x;
  const int lane = t & 63;
  const int wave = t >> 6;
  const int wr   = (wave >> 1) * 64;
  const int wc   = (wave & 1) * 64;
  const int ln   = lane & 15;
  const int qd   = lane >> 4;
  const int sw   = qd ^ (ln & 3) ^ (ln >> 2);   // swizzled k-slot for reads

  f32x4 acc[4][4];
  #pragma unroll
  for (int i = 0; i < 4; ++i)
    #pragma unroll
    for (int j = 0; j < 4; ++j) { f32x4 z = {0.f,0.f,0.f,0.f}; acc[i][j] = z; }

  // glld mapping: wave handles chunks {2w, 2w+1} of each plane; lane l ->
  // row 16c + (l>>2), global segment seg_src(l) (swizzle), LDS = base + l*16.
  const int c0   = wave * 2;
  const int arow = c0 * 16 + (lane >> 2);
  const int ab   = seg_src(lane) * 16;
  const char* gAh = (const char*)Ahb + (long long)arow * D_ * 2 + ab;
  const char* gAl = (const char*)Alb + (long long)arow * D_ * 2 + ab;
  const long long rstep = (long long)16 * D_ * 2;   // +16 rows (both dec2 & encF16)
  char* lAh = (char*)sAh + c0 * 1024 + lane * 16;
  char* lAl = (char*)sAl + c0 * 1024 + lane * 16;
  char* lB  = (char*)sB  + c0 * 1024 + lane * 16;

  const char* gB16 = nullptr;
  if constexpr (F16B) {
    const _Float16* Bb16 = B16 + (long long)bz * TK_ * D_ + (long long)n0 * D_;
    gB16 = (const char*)Bb16 + (long long)arow * D_ * 2 + ab;
  }

  // fallback B staging: thread t -> row t>>1, half t&1; swizzled store slots
  const float* Bb = Bf + (long long)bz * TK_ * D_ + (long long)n0 * D_;
  const int brow = t >> 1;
  const int bhf  = t & 1;
  const float* srcB = Bb + (long long)brow * D_ + bhf * 16;
  const int bh2 = (brow & 3) ^ ((brow >> 2) & 3);
  _Float16* dB0 = &sB[brow * SBK + ((2 * bhf    ) ^ bh2) * 8];
  _Float16* dB1 = &sB[brow * SBK + ((2 * bhf + 1) ^ bh2) * 8];

  for (int k0 = 0; k0 < D_; k0 += SBK) {
    glld16(gAh + (long long)k0 * 2, lAh);
    glld16(gAh + (long long)k0 * 2 + rstep, lAh + 1024);
    glld16(gAl + (long long)k0 * 2, lAl);
    glld16(gAl + (long long)k0 * 2 + rstep, lAl + 1024);
    if constexpr (F16B) {
      glld16(gB16 + (long long)k0 * 2, lB);
      glld16(gB16 + (long long)k0 * 2 + rstep, lB + 1024);
    } else {
      __align__(16) _Float16 hb[16];
      #pragma unroll
      for (int i = 0; i < 16; i += 4) {
        float4 v = *(const float4*)(srcB + k0 + i);
        hb[i+0] = (_Float16)v.x;
        hb[i+1] = (_Float16)v.y;
        hb[i+2] = (_Float16)v.z;
        hb[i+3] = (_Float16)v.w;
      }
      *(uint4*)dB0 = ((const uint4*)hb)[0];
      *(uint4*)dB1 = ((const uint4*)hb)[1];
    }
    __syncthreads();

    f16x8 fah[4], fal[4], fb[4];
    #pragma unroll
    for (int i = 0; i < 4; ++i) {
      int ra = (wr + i * 16 + ln) * SBK + sw * 8;
      int rb = (wc + i * 16 + ln) * SBK + sw * 8;
      fah[i] = *(const f16x8*)&sAh[ra];
      fal[i] = *(const f16x8*)&sAl[ra];
      fb[i]  = *(const f16x8*)&sB[rb];
    }
    #pragma unroll
    for (int i = 0; i < 4; ++i)
      #pragma unroll
      for (int j = 0; j < 4; ++j) {
        acc[i][j] = __builtin_amdgcn_mfma_f32_16x16x32_f16(fah[i], fb[j], acc[i][j], 0, 0, 0);
        acc[i][j] = __builtin_amdgcn_mfma_f32_16x16x32_f16(fal[i], fb[j], acc[i][j], 0, 0, 0);
      }
    __syncthreads();
  }

  float* Cb = C + (long long)bz * TQ_ * TK_;
  #pragma unroll
  for (int i = 0; i < 4; ++i)
    #pragma unroll
    for (int j = 0; j < 4; ++j)
      #pragma unroll
      for (int rg = 0; rg < 4; ++rg) {
        int row = m0 + wr + i * 16 + qd * 4 + rg;
        int col = n0 + wc + j * 16 + ln;
        Cb[(long long)row * TK_ + col] = acc[i][j][rg];
      }
}

// ---------------------------------------------------------------------------
// Row softmax in place (+ optional f16 copy for ctx GEMM)
// ---------------------------------------------------------------------------
template<bool WP16>
__global__ __launch_bounds__(256) void softmax_kernel(
    float* __restrict__ P, _Float16* __restrict__ P16)
{
  __shared__ float red[8];
  float* p = P + (long long)blockIdx.x * TK_;
  const int t    = threadIdx.x;
  const int lane = t & 63;
  const int wave = t >> 6;

  float4 v[4];
  float mx = -3.0e38f;
  #pragma unroll
  for (int i = 0; i < 4; ++i) {
    v[i] = *(const float4*)&p[i * 1024 + t * 4];
    mx = fmaxf(mx, fmaxf(fmaxf(v[i].x, v[i].y), fmaxf(v[i].z, v[i].w)));
  }
  #pragma unroll
  for (int o = 32; o > 0; o >>= 1) mx = fmaxf(mx, __shfl_xor(mx, o, 64));
  if (lane == 0) red[wave] = mx;
  __syncthreads();
  mx = fmaxf(fmaxf(red[0], red[1]), fmaxf(red[2], red[3]));

  float s = 0.f;
  #pragma unroll
  for (int i = 0; i < 4; ++i) {
    v[i].x = __expf(v[i].x - mx);
    v[i].y = __expf(v[i].y - mx);
    v[i].z = __expf(v[i].z - mx);
    v[i].w = __expf(v[i].w - mx);
    s += (v[i].x + v[i].y) + (v[i].z + v[i].w);
  }
  #pragma unroll
  for (int o = 32; o > 0; o >>= 1) s += __shfl_xor(s, o, 64);
  if (lane == 0) red[4 + wave] = s;
  __syncthreads();
  s = (red[4] + red[5]) + (red[6] + red[7]);
  const float inv = 1.0f / s;

  _Float16* p16 = WP16 ? (P16 + (long long)blockIdx.x * TK_) : nullptr;
  #pragma unroll
  for (int i = 0; i < 4; ++i) {
    v[i].x *= inv; v[i].y *= inv; v[i].z *= inv; v[i].w *= inv;
    *(float4*)&p[i * 1024 + t * 4] = v[i];
    if constexpr (WP16) {
      union { _Float16 h[4]; uint2 u; } pk;
      pk.h[0] = (_Float16)v[i].x;
      pk.h[1] = (_Float16)v[i].y;
      pk.h[2] = (_Float16)v[i].z;
      pk.h[3] = (_Float16)v[i].w;
      *(uint2*)&p16[i * 1024 + t * 4] = pk.u;
    }
  }
}

// ---------------------------------------------------------------------------
// Context GEMM: C[b][q][d] = sum_k P[b,q,k] * encT[b,d,k]
// B via glld (swizzled source); A via glld from P16 (fast) or in-loop cvt of
// fp32 P (fallback). LDS tiles XOR-swizzled.
// ---------------------------------------------------------------------------
#define CBM 64
#define CBN 256
#define CBK 32

template<bool F16A>
__global__ __launch_bounds__(512) void gemm_ctx_kernel(
    const float* __restrict__ P, const _Float16* __restrict__ P16,
    const _Float16* __restrict__ ET, float* __restrict__ C)
{
  __shared__ _Float16 sA[CBM * CBK];   // 4 KB
  __shared__ _Float16 sB[CBN * CBK];   // 16 KB

  const int bz = blockIdx.z;
  const int m0 = blockIdx.y * CBM;
  const int n0 = blockIdx.x * CBN;
  const float*    Pb = P  + (long long)bz * TQ_ * TK_ + (long long)m0 * TK_;
  const _Float16* Eb = ET + (long long)bz * D_ * TK_  + (long long)n0 * TK_;

  const int t    = threadIdx.x;
  const int lane = t & 63;
  const int wave = t >> 6;
  const int wr   = (wave >> 2) * 32;   // 0,32
  const int wc   = (wave & 3) * 64;    // 0,64,128,192
  const int ln   = lane & 15;
  const int qd   = lane >> 4;
  const int sw   = qd ^ (ln & 3) ^ (ln >> 2);

  f32x4 acc[2][4];
  #pragma unroll
  for (int i = 0; i < 2; ++i)
    #pragma unroll
    for (int j = 0; j < 4; ++j) { f32x4 z = {0.f,0.f,0.f,0.f}; acc[i][j] = z; }

  // glld B: 16 chunks of 1 KB; wave handles {2w, 2w+1}; swizzled source segs
  const int c0   = wave * 2;
  const int brow = c0 * 16 + (lane >> 2);
  const int bb   = seg_src(lane) * 16;
  const char* gB = (const char*)Eb + (long long)brow * TK_ * 2 + bb;
  const long long rstep = (long long)16 * TK_ * 2;
  char* lB = (char*)sB + c0 * 1024 + lane * 16;

  // A fast path: 4 chunks; waves 0..3 handle chunk=wave
  const char* gA16 = nullptr;
  char* lA16 = nullptr;
  if constexpr (F16A) {
    const _Float16* Pb16 = P16 + (long long)bz * TQ_ * TK_ + (long long)m0 * TK_;
    const int acrow = wave * 16 + (lane >> 2);
    gA16 = (const char*)Pb16 + (long long)acrow * TK_ * 2 + bb;
    lA16 = (char*)sA + wave * 1024 + lane * 16;
  }
  // A fallback: thread -> row t>>3 (0..63), 8B granule (t&7), swizzled slot
  const int arow = t >> 3;
  const int aseg = t & 7;
  const float* gA = Pb + (long long)arow * TK_ + aseg * 4;
  const int ah2 = (arow & 3) ^ ((arow >> 2) & 3);
  _Float16* lA = &sA[arow * CBK + (((aseg >> 1) ^ ah2) * 8) + (aseg & 1) * 4];

  for (int k0 = 0; k0 < TK_; k0 += CBK) {
    glld16(gB + (long long)k0 * 2, lB);
    glld16(gB + (long long)k0 * 2 + rstep, lB + 1024);
    if constexpr (F16A) {
      if (wave < 4) glld16(gA16 + (long long)k0 * 2, lA16);
    } else {
      float4 v = *(const float4*)(gA + k0);
      union { _Float16 h[4]; uint2 u; } pk;
      pk.h[0] = (_Float16)v.x;
      pk.h[1] = (_Float16)v.y;
      pk.h[2] = (_Float16)v.z;
      pk.h[3] = (_Float16)v.w;
      *(uint2*)lA = pk.u;
    }
    __syncthreads();

    f16x8 fa[2], fb[4];
    #pragma unroll
    for (int i = 0; i < 2; ++i)
      fa[i] = *(const f16x8*)&sA[(wr + i * 16 + ln) * CBK + sw * 8];
    #pragma unroll
    for (int j = 0; j < 4; ++j)
      fb[j] = *(const f16x8*)&sB[(wc + j * 16 + ln) * CBK + sw * 8];
    #pragma unroll
    for (int i = 0; i < 2; ++i)
      #pragma unroll
      for (int j = 0; j < 4; ++j)
        acc[i][j] = __builtin_amdgcn_mfma_f32_16x16x32_f16(fa[i], fb[j], acc[i][j], 0, 0, 0);
    __syncthreads();
  }

  float* Cb = C + (long long)bz * TQ_ * D_;
  #pragma unroll
  for (int i = 0; i < 2; ++i)
    #pragma unroll
    for (int j = 0; j < 4; ++j)
      #pragma unroll
      for (int rg = 0; rg < 4; ++rg) {
        int row = m0 + wr + i * 16 + qd * 4 + rg;
        int col = n0 + wc + j * 16 + ln;
        Cb[(long long)row * D_ + col] = acc[i][j][rg];
      }
}

// ---------------------------------------------------------------------------
extern "C" void kernel_launch(void* const* d_in, const int* in_sizes, int n_in,
                              void* d_out, int out_size, void* d_ws, size_t ws_size,
                              hipStream_t stream) {
  (void)in_sizes; (void)n_in; (void)out_size;
  const float* dec = (const float*)d_in[0];   // [16,1024,512]
  const float* enc = (const float*)d_in[1];   // [16,4096,512]
  const float* Wa  = (const float*)d_in[2];   // [512,512]
  // b_a constant along softmax axis -> cancels exactly; unused.

  float* ctx   = (float*)d_out;                                   // [16,1024,512]
  float* align = ctx + (long long)B_ * TQ_ * D_;                  // [16,1024,4096]

  char* ws = (char*)d_ws;
  const size_t SZ_ENCT = (size_t)B_ * D_ * TK_ * 2;   // 67,108,864
  const size_t SZ_DEC2 = (size_t)B_ * TQ_ * D_ * 2;   // 16,777,216
  const size_t SZ_ENCF = (size_t)B_ * TK_ * D_ * 2;   // 67,108,864
  const size_t SZ_P16  = (size_t)B_ * TQ_ * TK_ * 2;  // 134,217,728

  _Float16* encT  = (_Float16*)(ws);
  _Float16* dec2h = (_Float16*)(ws + SZ_ENCT);
  _Float16* dec2l = (_Float16*)(ws + SZ_ENCT + SZ_DEC2);
  _Float16* encF  = (_Float16*)(ws + SZ_ENCT + 2 * SZ_DEC2);
  // P16 overlays dec2h/dec2l/encF -- all dead once score finishes (stream order)
  _Float16* p16   = (_Float16*)(ws + SZ_ENCT);

  const bool mid  = ws_size >= SZ_ENCT + 2 * SZ_DEC2 + SZ_ENCF;  // 167.8 MB
  const bool full = ws_size >= SZ_ENCT + SZ_P16;                  // 201.3 MB

  // 1) encT[b][d][k] = f16(enc[b][k][d]); also encF16[b][k][d] if room
  transpose_conv_kernel<<<dim3(TK_ / 64, D_ / 64, B_), 256, 0, stream>>>(
      enc, encT, mid ? encF : nullptr);

  // 2) dec2 = dec @ W^T (split-bf16 triple), epilogue -> f16 hi/lo planes
  gemm_dec2_kernel<<<dim3(D_ / DBN, (B_ * TQ_) / DBM, 1), 256, 0, stream>>>(
      dec, Wa, dec2h, dec2l);

  // 3) score = dec2 @ enc^T (f16: Ah*B + Al*B)
  if (mid)
    gemm_score_kernel<true><<<dim3(TK_ / SBN, TQ_ / SBM, B_), 256, 0, stream>>>(
        dec2h, dec2l, enc, encF, align);
  else
    gemm_score_kernel<false><<<dim3(TK_ / SBN, TQ_ / SBM, B_), 256, 0, stream>>>(
        dec2h, dec2l, enc, nullptr, align);

  // 4) softmax rows in place (+ f16 copy if room)
  if (full)
    softmax_kernel<true><<<B_ * TQ_, 256, 0, stream>>>(align, p16);
  else
    softmax_kernel<false><<<B_ * TQ_, 256, 0, stream>>>(align, nullptr);

  // 5) ctx = P @ encT^T (f16)
  if (full)
    gemm_ctx_kernel<true><<<dim3(D_ / CBN, TQ_ / CBM, B_), 512, 0, stream>>>(
        align, p16, encT, ctx);
  else
    gemm_ctx_kernel<false><<<dim3(D_ / CBN, TQ_ / CBM, B_), 512, 0, stream>>>(
        align, nullptr, encT, ctx);
}

// Round 2
// 848.132 us; speedup vs baseline: 1.0464x; 1.0215x over previous
//
#include <hip/hip_runtime.h>
#include <hip/hip_bf16.h>

#define B_  16
#define TQ_ 1024
#define TK_ 4096
#define D_  512

typedef unsigned short u16;
typedef __attribute__((ext_vector_type(8))) short short8;      // 8 bf16
typedef __attribute__((ext_vector_type(8))) _Float16 f16x8;    // 8 f16 (4 VGPRs)
typedef __attribute__((ext_vector_type(4))) float f32x4;

__device__ __forceinline__ u16 bf16_rne(float x) {
  unsigned u = __float_as_uint(x);
  u += 0x7FFFu + ((u >> 16) & 1u);
  return (u16)(u >> 16);
}
__device__ __forceinline__ float bf16_as_f32(u16 h) {
  return __uint_as_float(((unsigned)h) << 16);
}
__device__ __forceinline__ void split_bf16(float x, u16& h, u16& l) {
  u16 hh = bf16_rne(x);
  h = hh;
  l = bf16_rne(x - bf16_as_f32(hh));
}

// async global->LDS, 16B per lane; LDS dest must be wave-contiguous (base + lane*16)
__device__ __forceinline__ void glld16(const void* g, void* lds) {
  __builtin_amdgcn_global_load_lds(
      (const __attribute__((address_space(1))) unsigned int*)g,
      (__attribute__((address_space(3))) unsigned int*)lds, 16, 0, 0);
}

// 4-slot swizzle (64B rows, SBK=32): LDS slot (row,s) holds global segment
// s ^ (row&3) ^ ((row>>2)&3). Staging lane l fetches segment seg_src4(l);
// reads use slot qd ^ (ln&3) ^ (ln>>2). Conflict-free (verified by bank enum).
__device__ __forceinline__ int seg_src4(int l) {
  return (l & 3) ^ ((l >> 2) & 3) ^ ((l >> 4) & 3);
}

// ---------------------------------------------------------------------------
// enc [b][k][d] fp32 -> encT [b][d][k] f16  (+ optional encF16 [b][k][d] f16)
// ---------------------------------------------------------------------------
__global__ __launch_bounds__(256) void transpose_conv_kernel(
    const float* __restrict__ E, _Float16* __restrict__ ET,
    _Float16* __restrict__ EF)
{
  __shared__ float tile[64][65];
  const int b  = blockIdx.z;
  const int k0 = blockIdx.x * 64;
  const int d0 = blockIdx.y * 64;
  const float* Eb = E + (long long)b * TK_ * D_;
  _Float16* ETb = ET + (long long)b * D_ * TK_;

  const int t  = threadIdx.x;
  const int r  = t >> 2;          // 0..63
  const int c4 = (t & 3) * 16;    // 0,16,32,48

  __align__(16) _Float16 g[16];
  #pragma unroll
  for (int i = 0; i < 16; i += 4) {
    float4 v = *(const float4*)&Eb[(long long)(k0 + r) * D_ + d0 + c4 + i];
    tile[r][c4 + i + 0] = v.x;
    tile[r][c4 + i + 1] = v.y;
    tile[r][c4 + i + 2] = v.z;
    tile[r][c4 + i + 3] = v.w;
    g[i + 0] = (_Float16)v.x;
    g[i + 1] = (_Float16)v.y;
    g[i + 2] = (_Float16)v.z;
    g[i + 3] = (_Float16)v.w;
  }
  if (EF) {
    _Float16* EFb = EF + (long long)b * TK_ * D_;
    uint4* dstF = (uint4*)&EFb[(long long)(k0 + r) * D_ + d0 + c4];
    dstF[0] = ((const uint4*)g)[0];
    dstF[1] = ((const uint4*)g)[1];
  }
  __syncthreads();

  __align__(16) _Float16 h[16];
  #pragma unroll
  for (int i = 0; i < 16; ++i) h[i] = (_Float16)tile[c4 + i][r];
  uint4* dst = (uint4*)&ETb[(long long)(d0 + r) * TK_ + k0 + c4];
  dst[0] = ((const uint4*)h)[0];
  dst[1] = ((const uint4*)h)[1];
}

// ---------------------------------------------------------------------------
// dec2 = dec @ W^T  (split-bf16 triple), epilogue emits f16 hi/lo
// ---------------------------------------------------------------------------
#define DBM 128
#define DBN 128
#define DBK 32
#define DPAD 40

__global__ __launch_bounds__(256) void gemm_dec2_kernel(
    const float* __restrict__ A, const float* __restrict__ Bm,
    _Float16* __restrict__ Ch, _Float16* __restrict__ Cl)
{
  __shared__ u16 Ah[DBM * DPAD];
  __shared__ u16 Al[DBM * DPAD];
  __shared__ u16 Bh[DBN * DPAD];
  __shared__ u16 Bl[DBN * DPAD];

  const float* Ab = A  + (long long)(blockIdx.y * DBM) * D_;
  const float* Bb = Bm + (long long)(blockIdx.x * DBN) * D_;

  const int t    = threadIdx.x;
  const int r    = t >> 1;
  const int hf   = t & 1;
  const int lane = t & 63;
  const int wave = t >> 6;
  const int wr   = (wave >> 1) * 64;
  const int wc   = (wave & 1) * 64;
  const int ln   = lane & 15;
  const int qd   = lane >> 4;

  f32x4 acc[4][4];
  #pragma unroll
  for (int i = 0; i < 4; ++i)
    #pragma unroll
    for (int j = 0; j < 4; ++j) { f32x4 z = {0.f,0.f,0.f,0.f}; acc[i][j] = z; }

  const float* srcA = Ab + (long long)r * D_ + hf * 16;
  const float* srcB = Bb + (long long)r * D_ + hf * 16;
  u16* dAh = &Ah[r * DPAD + hf * 16];
  u16* dAl = &Al[r * DPAD + hf * 16];
  u16* dBh = &Bh[r * DPAD + hf * 16];
  u16* dBl = &Bl[r * DPAD + hf * 16];

  for (int k0 = 0; k0 < D_; k0 += DBK) {
    {
      __align__(16) u16 h[16], l[16];
      #pragma unroll
      for (int i = 0; i < 16; i += 4) {
        float4 v = *(const float4*)(srcA + k0 + i);
        split_bf16(v.x, h[i+0], l[i+0]);
        split_bf16(v.y, h[i+1], l[i+1]);
        split_bf16(v.z, h[i+2], l[i+2]);
        split_bf16(v.w, h[i+3], l[i+3]);
      }
      ((uint4*)dAh)[0] = ((const uint4*)h)[0];
      ((uint4*)dAh)[1] = ((const uint4*)h)[1];
      ((uint4*)dAl)[0] = ((const uint4*)l)[0];
      ((uint4*)dAl)[1] = ((const uint4*)l)[1];
      #pragma unroll
      for (int i = 0; i < 16; i += 4) {
        float4 v = *(const float4*)(srcB + k0 + i);
        split_bf16(v.x, h[i+0], l[i+0]);
        split_bf16(v.y, h[i+1], l[i+1]);
        split_bf16(v.z, h[i+2], l[i+2]);
        split_bf16(v.w, h[i+3], l[i+3]);
      }
      ((uint4*)dBh)[0] = ((const uint4*)h)[0];
      ((uint4*)dBh)[1] = ((const uint4*)h)[1];
      ((uint4*)dBl)[0] = ((const uint4*)l)[0];
      ((uint4*)dBl)[1] = ((const uint4*)l)[1];
    }
    __syncthreads();

    short8 fah[4], fal[4], fbh[4], fbl[4];
    #pragma unroll
    for (int i = 0; i < 4; ++i) {
      int ra = (wr + i * 16 + ln) * DPAD + qd * 8;
      int rb = (wc + i * 16 + ln) * DPAD + qd * 8;
      fah[i] = *(const short8*)&Ah[ra];
      fal[i] = *(const short8*)&Al[ra];
      fbh[i] = *(const short8*)&Bh[rb];
      fbl[i] = *(const short8*)&Bl[rb];
    }
    #pragma unroll
    for (int i = 0; i < 4; ++i)
      #pragma unroll
      for (int j = 0; j < 4; ++j) {
        acc[i][j] = __builtin_amdgcn_mfma_f32_16x16x32_bf16(fah[i], fbh[j], acc[i][j], 0, 0, 0);
        acc[i][j] = __builtin_amdgcn_mfma_f32_16x16x32_bf16(fah[i], fbl[j], acc[i][j], 0, 0, 0);
        acc[i][j] = __builtin_amdgcn_mfma_f32_16x16x32_bf16(fal[i], fbh[j], acc[i][j], 0, 0, 0);
      }
    __syncthreads();
  }

  const int m0 = blockIdx.y * DBM;
  const int n0 = blockIdx.x * DBN;
  #pragma unroll
  for (int i = 0; i < 4; ++i)
    #pragma unroll
    for (int j = 0; j < 4; ++j)
      #pragma unroll
      for (int rg = 0; rg < 4; ++rg) {
        int row = m0 + wr + i * 16 + qd * 4 + rg;
        int col = n0 + wc + j * 16 + ln;
        float x = acc[i][j][rg];
        _Float16 h = (_Float16)x;
        _Float16 l = (_Float16)(x - (float)h);
        long long idx = (long long)row * D_ + col;
        Ch[idx] = h;
        Cl[idx] = l;
      }
}

// ---------------------------------------------------------------------------
// Score GEMM: C[b][q][k] = sum_d dec2[b,q,d] * enc[b,k,d]
// 2-phase double-buffered: STAGE(next) issued before compute(cur); ONE
// __syncthreads per k-iter (drains the prefetch vmcnt). XOR-swizzled tiles.
// ---------------------------------------------------------------------------
#define SBM 128
#define SBN 128
#define SBK 32
#define S_NT (D_ / SBK)   // 16

template<bool F16B>
__global__ __launch_bounds__(256) void gemm_score_kernel(
    const _Float16* __restrict__ A_h, const _Float16* __restrict__ A_l,
    const float* __restrict__ Bf, const _Float16* __restrict__ B16,
    float* __restrict__ C)
{
  __shared__ _Float16 sAh[2][SBM * SBK];   // 2 x 8 KB
  __shared__ _Float16 sAl[2][SBM * SBK];   // 2 x 8 KB
  __shared__ _Float16 sB [2][SBN * SBK];   // 2 x 8 KB

  const int bz = blockIdx.z;
  const int m0 = blockIdx.y * SBM;
  const int n0 = blockIdx.x * SBN;
  const _Float16* Ahb = A_h + (long long)bz * TQ_ * D_ + (long long)m0 * D_;
  const _Float16* Alb = A_l + (long long)bz * TQ_ * D_ + (long long)m0 * D_;

  const int t    = threadIdx.x;
  const int lane = t & 63;
  const int wave = t >> 6;
  const int wr   = (wave >> 1) * 64;
  const int wc   = (wave & 1) * 64;
  const int ln   = lane & 15;
  const int qd   = lane >> 4;
  const int sw   = qd ^ (ln & 3) ^ (ln >> 2);   // swizzled k-slot for reads

  f32x4 acc[4][4];
  #pragma unroll
  for (int i = 0; i < 4; ++i)
    #pragma unroll
    for (int j = 0; j < 4; ++j) { f32x4 z = {0.f,0.f,0.f,0.f}; acc[i][j] = z; }

  // glld mapping: wave handles chunks {2w,2w+1}; lane l -> row 16c+(l>>2),
  // global segment seg_src4(l), LDS linear dest = base + l*16.
  const int c0   = wave * 2;
  const int arow = c0 * 16 + (lane >> 2);
  const int ab   = seg_src4(lane) * 16;
  const char* gAh = (const char*)Ahb + (long long)arow * D_ * 2 + ab;
  const char* gAl = (const char*)Alb + (long long)arow * D_ * 2 + ab;
  const long long rstep = (long long)16 * D_ * 2;   // +16 rows
  const int dstoff = c0 * 1024 + lane * 16;

  const char* gB16 = nullptr;
  if constexpr (F16B) {
    const _Float16* Bb16 = B16 + (long long)bz * TK_ * D_ + (long long)n0 * D_;
    gB16 = (const char*)Bb16 + (long long)arow * D_ * 2 + ab;
  }

  // fallback B staging: thread t -> row t>>1, half t&1; swizzled store slots
  const float* Bb = Bf + (long long)bz * TK_ * D_ + (long long)n0 * D_;
  const int brow = t >> 1;
  const int bhf  = t & 1;
  const float* srcB = Bb + (long long)brow * D_ + bhf * 16;
  const int bh2 = (brow & 3) ^ ((brow >> 2) & 3);
  const int db0 = brow * SBK + ((2 * bhf    ) ^ bh2) * 8;
  const int db1 = brow * SBK + ((2 * bhf + 1) ^ bh2) * 8;

  auto stage = [&](int buf, int k0) {
    const long long ko = (long long)k0 * 2;
    char* dAh = (char*)sAh[buf] + dstoff;
    char* dAl = (char*)sAl[buf] + dstoff;
    glld16(gAh + ko, dAh);
    glld16(gAh + ko + rstep, dAh + 1024);
    glld16(gAl + ko, dAl);
    glld16(gAl + ko + rstep, dAl + 1024);
    if constexpr (F16B) {
      char* dBv = (char*)sB[buf] + dstoff;
      glld16(gB16 + ko, dBv);
      glld16(gB16 + ko + rstep, dBv + 1024);
    } else {
      __align__(16) _Float16 hb[16];
      #pragma unroll
      for (int i = 0; i < 16; i += 4) {
        float4 v = *(const float4*)(srcB + k0 + i);
        hb[i+0] = (_Float16)v.x;
        hb[i+1] = (_Float16)v.y;
        hb[i+2] = (_Float16)v.z;
        hb[i+3] = (_Float16)v.w;
      }
      *(uint4*)&sB[buf][db0] = ((const uint4*)hb)[0];
      *(uint4*)&sB[buf][db1] = ((const uint4*)hb)[1];
    }
  };

  stage(0, 0);
  __syncthreads();

  int cur = 0;
  for (int tt = 0; tt < S_NT; ++tt) {
    if (tt + 1 < S_NT) stage(cur ^ 1, (tt + 1) * SBK);

    const _Float16* bAh = sAh[cur];
    const _Float16* bAl = sAl[cur];
    const _Float16* bBv = sB[cur];
    f16x8 fah[4], fal[4], fb[4];
    #pragma unroll
    for (int i = 0; i < 4; ++i) {
      int ra = (wr + i * 16 + ln) * SBK + sw * 8;
      int rb = (wc + i * 16 + ln) * SBK + sw * 8;
      fah[i] = *(const f16x8*)&bAh[ra];
      fal[i] = *(const f16x8*)&bAl[ra];
      fb[i]  = *(const f16x8*)&bBv[rb];
    }
    #pragma unroll
    for (int i = 0; i < 4; ++i)
      #pragma unroll
      for (int j = 0; j < 4; ++j) {
        acc[i][j] = __builtin_amdgcn_mfma_f32_16x16x32_f16(fah[i], fb[j], acc[i][j], 0, 0, 0);
        acc[i][j] = __builtin_amdgcn_mfma_f32_16x16x32_f16(fal[i], fb[j], acc[i][j], 0, 0, 0);
      }
    __syncthreads();   // drains prefetch vmcnt + all lgkm; next buf ready
    cur ^= 1;
  }

  float* Cb = C + (long long)bz * TQ_ * TK_;
  #pragma unroll
  for (int i = 0; i < 4; ++i)
    #pragma unroll
    for (int j = 0; j < 4; ++j)
      #pragma unroll
      for (int rg = 0; rg < 4; ++rg) {
        int row = m0 + wr + i * 16 + qd * 4 + rg;
        int col = n0 + wc + j * 16 + ln;
        Cb[(long long)row * TK_ + col] = acc[i][j][rg];
      }
}

// ---------------------------------------------------------------------------
// Row softmax in place (+ optional f16 copy for ctx GEMM)
// ---------------------------------------------------------------------------
template<bool WP16>
__global__ __launch_bounds__(256) void softmax_kernel(
    float* __restrict__ P, _Float16* __restrict__ P16)
{
  __shared__ float red[8];
  float* p = P + (long long)blockIdx.x * TK_;
  const int t    = threadIdx.x;
  const int lane = t & 63;
  const int wave = t >> 6;

  float4 v[4];
  float mx = -3.0e38f;
  #pragma unroll
  for (int i = 0; i < 4; ++i) {
    v[i] = *(const float4*)&p[i * 1024 + t * 4];
    mx = fmaxf(mx, fmaxf(fmaxf(v[i].x, v[i].y), fmaxf(v[i].z, v[i].w)));
  }
  #pragma unroll
  for (int o = 32; o > 0; o >>= 1) mx = fmaxf(mx, __shfl_xor(mx, o, 64));
  if (lane == 0) red[wave] = mx;
  __syncthreads();
  mx = fmaxf(fmaxf(red[0], red[1]), fmaxf(red[2], red[3]));

  float s = 0.f;
  #pragma unroll
  for (int i = 0; i < 4; ++i) {
    v[i].x = __expf(v[i].x - mx);
    v[i].y = __expf(v[i].y - mx);
    v[i].z = __expf(v[i].z - mx);
    v[i].w = __expf(v[i].w - mx);
    s += (v[i].x + v[i].y) + (v[i].z + v[i].w);
  }
  #pragma unroll
  for (int o = 32; o > 0; o >>= 1) s += __shfl_xor(s, o, 64);
  if (lane == 0) red[4 + wave] = s;
  __syncthreads();
  s = (red[4] + red[5]) + (red[6] + red[7]);
  const float inv = 1.0f / s;

  _Float16* p16 = WP16 ? (P16 + (long long)blockIdx.x * TK_) : nullptr;
  #pragma unroll
  for (int i = 0; i < 4; ++i) {
    v[i].x *= inv; v[i].y *= inv; v[i].z *= inv; v[i].w *= inv;
    *(float4*)&p[i * 1024 + t * 4] = v[i];
    if constexpr (WP16) {
      union { _Float16 h[4]; uint2 u; } pk;
      pk.h[0] = (_Float16)v[i].x;
      pk.h[1] = (_Float16)v[i].y;
      pk.h[2] = (_Float16)v[i].z;
      pk.h[3] = (_Float16)v[i].w;
      *(uint2*)&p16[i * 1024 + t * 4] = pk.u;
    }
  }
}

// ---------------------------------------------------------------------------
// Context GEMM: C[b][q][d] = sum_k P[b,q,k] * encT[b,d,k]
// Tile 64x256, CBK=64, 512 thr (8 waves 2x4), 2-phase double-buffered,
// 8-slot XOR swizzle (128B rows). XCD-chunked 1-D grid, m-fastest decode.
// ---------------------------------------------------------------------------
#define CBM 64
#define CBN 256
#define CBK 64
#define C_NT (TK_ / CBK)   // 64

template<bool F16A>
__global__ __launch_bounds__(512) void gemm_ctx_kernel(
    const float* __restrict__ P, const _Float16* __restrict__ P16,
    const _Float16* __restrict__ ET, float* __restrict__ C)
{
  __shared__ _Float16 sA[2][CBM * CBK];   // 2 x 8 KB
  __shared__ _Float16 sB[2][CBN * CBK];   // 2 x 32 KB

  // 512 blocks = 8 XCD chunks of 64; within a chunk m is fastest so the 16
  // m-blocks sharing one encT panel co-reside on an XCD.
  const int bid = blockIdx.x;
  const int s   = (bid & 7) * 64 + (bid >> 3);
  const int m0  = (s & 15) * CBM;
  const int n0  = ((s >> 4) & 1) * CBN;
  const int bz  = s >> 5;

  const float*    Pb = P  + (long long)bz * TQ_ * TK_ + (long long)m0 * TK_;
  const _Float16* Eb = ET + (long long)bz * D_ * TK_  + (long long)n0 * TK_;

  const int t    = threadIdx.x;
  const int lane = t & 63;
  const int wave = t >> 6;
  const int wr   = (wave >> 2) * 32;   // 0,32
  const int wc   = (wave & 3) * 64;    // 0,64,128,192
  const int ln   = lane & 15;
  const int qd   = lane >> 4;
  const int l7   = ln & 7;

  f32x4 acc[2][4];
  #pragma unroll
  for (int i = 0; i < 2; ++i)
    #pragma unroll
    for (int j = 0; j < 4; ++j) { f32x4 z = {0.f,0.f,0.f,0.f}; acc[i][j] = z; }

  // staging geometry: 1 KB chunk = 8 rows x 128 B; lane l -> row 8c+(l>>3),
  // stored slot l&7, fetched global segment (l&7)^((l>>3)&7).
  const int l8   = lane >> 3;          // 0..7
  const int sseg = (lane & 7) ^ l8;    // inverse-swizzled global segment
  // B: wave handles 4 chunks {4w..4w+3} -> rows 32w+8j+l8
  const char* gB = (const char*)Eb + ((long long)(wave * 32 + l8) * TK_) * 2 + sseg * 16;
  const long long bstep = (long long)8 * TK_ * 2;
  const int bdst = wave * 4096 + lane * 16;
  // A fast path: wave handles chunk w -> rows 8w+l8
  const char* gA16 = nullptr;
  if constexpr (F16A) {
    const _Float16* Pb16 = P16 + (long long)bz * TQ_ * TK_ + (long long)m0 * TK_;
    gA16 = (const char*)Pb16 + ((long long)(wave * 8 + l8) * TK_) * 2 + sseg * 16;
  }
  const int adst = wave * 1024 + lane * 16;

  // A fallback: thread t -> row t>>3 (0..63), logical slot t&7 (8 floats)
  const int arowf = t >> 3;
  const int asegf = t & 7;
  const float* gAf = Pb + (long long)arowf * TK_ + asegf * 8;
  const int afoff = arowf * CBK + ((asegf ^ (arowf & 7)) * 8);

  auto stage = [&](int buf, int k0) {
    const long long ko = (long long)k0 * 2;
    char* dB = (char*)sB[buf] + bdst;
    #pragma unroll
    for (int j = 0; j < 4; ++j)
      glld16(gB + ko + j * bstep, dB + j * 1024);
    if constexpr (F16A) {
      glld16(gA16 + ko, (char*)sA[buf] + adst);
    } else {
      float4 v0 = *(const float4*)(gAf + k0);
      float4 v1 = *(const float4*)(gAf + k0 + 4);
      __align__(16) _Float16 hb[8];
      hb[0] = (_Float16)v0.x; hb[1] = (_Float16)v0.y;
      hb[2] = (_Float16)v0.z; hb[3] = (_Float16)v0.w;
      hb[4] = (_Float16)v1.x; hb[5] = (_Float16)v1.y;
      hb[6] = (_Float16)v1.z; hb[7] = (_Float16)v1.w;
      *(uint4*)&sA[buf][afoff] = *(const uint4*)hb;
    }
  };

  stage(0, 0);
  __syncthreads();

  int cur = 0;
  for (int tt = 0; tt < C_NT; ++tt) {
    if (tt + 1 < C_NT) stage(cur ^ 1, (tt + 1) * CBK);

    const _Float16* bA  = sA[cur];
    const _Float16* bBv = sB[cur];
    f16x8 fa[2][2], fb[4][2];
    #pragma unroll
    for (int i = 0; i < 2; ++i)
      #pragma unroll
      for (int kk = 0; kk < 2; ++kk)
        fa[i][kk] = *(const f16x8*)&bA[(wr + i * 16 + ln) * CBK + (((kk * 4 + qd) ^ l7) * 8)];
    #pragma unroll
    for (int j = 0; j < 4; ++j)
      #pragma unroll
      for (int kk = 0; kk < 2; ++kk)
        fb[j][kk] = *(const f16x8*)&bBv[(wc + j * 16 + ln) * CBK + (((kk * 4 + qd) ^ l7) * 8)];
    #pragma unroll
    for (int i = 0; i < 2; ++i)
      #pragma unroll
      for (int j = 0; j < 4; ++j)
        #pragma unroll
        for (int kk = 0; kk < 2; ++kk)
          acc[i][j] = __builtin_amdgcn_mfma_f32_16x16x32_f16(fa[i][kk], fb[j][kk], acc[i][j], 0, 0, 0);
    __syncthreads();
    cur ^= 1;
  }

  float* Cb = C + (long long)bz * TQ_ * D_;
  #pragma unroll
  for (int i = 0; i < 2; ++i)
    #pragma unroll
    for (int j = 0; j < 4; ++j)
      #pragma unroll
      for (int rg = 0; rg < 4; ++rg) {
        int row = m0 + wr + i * 16 + qd * 4 + rg;
        int col = n0 + wc + j * 16 + ln;
        Cb[(long long)row * D_ + col] = acc[i][j][rg];
      }
}

// ---------------------------------------------------------------------------
extern "C" void kernel_launch(void* const* d_in, const int* in_sizes, int n_in,
                              void* d_out, int out_size, void* d_ws, size_t ws_size,
                              hipStream_t stream) {
  (void)in_sizes; (void)n_in; (void)out_size;
  const float* dec = (const float*)d_in[0];   // [16,1024,512]
  const float* enc = (const float*)d_in[1];   // [16,4096,512]
  const float* Wa  = (const float*)d_in[2];   // [512,512]
  // b_a constant along softmax axis -> cancels exactly; unused.

  float* ctx   = (float*)d_out;                                   // [16,1024,512]
  float* align = ctx + (long long)B_ * TQ_ * D_;                  // [16,1024,4096]

  char* ws = (char*)d_ws;
  const size_t SZ_ENCT = (size_t)B_ * D_ * TK_ * 2;   // 67,108,864
  const size_t SZ_DEC2 = (size_t)B_ * TQ_ * D_ * 2;   // 16,777,216
  const size_t SZ_ENCF = (size_t)B_ * TK_ * D_ * 2;   // 67,108,864
  const size_t SZ_P16  = (size_t)B_ * TQ_ * TK_ * 2;  // 134,217,728

  _Float16* encT  = (_Float16*)(ws);
  _Float16* dec2h = (_Float16*)(ws + SZ_ENCT);
  _Float16* dec2l = (_Float16*)(ws + SZ_ENCT + SZ_DEC2);
  _Float16* encF  = (_Float16*)(ws + SZ_ENCT + 2 * SZ_DEC2);
  // P16 overlays dec2h/dec2l/encF -- all dead once score finishes (stream order)
  _Float16* p16   = (_Float16*)(ws + SZ_ENCT);

  const bool mid  = ws_size >= SZ_ENCT + 2 * SZ_DEC2 + SZ_ENCF;  // 167.8 MB
  const bool full = ws_size >= SZ_ENCT + SZ_P16;                  // 201.3 MB

  // 1) encT[b][d][k] = f16(enc[b][k][d]); also encF16[b][k][d] if room
  transpose_conv_kernel<<<dim3(TK_ / 64, D_ / 64, B_), 256, 0, stream>>>(
      enc, encT, mid ? encF : nullptr);

  // 2) dec2 = dec @ W^T (split-bf16 triple), epilogue -> f16 hi/lo planes
  gemm_dec2_kernel<<<dim3(D_ / DBN, (B_ * TQ_) / DBM, 1), 256, 0, stream>>>(
      dec, Wa, dec2h, dec2l);

  // 3) score = dec2 @ enc^T (f16: Ah*B + Al*B)
  if (mid)
    gemm_score_kernel<true><<<dim3(TK_ / SBN, TQ_ / SBM, B_), 256, 0, stream>>>(
        dec2h, dec2l, enc, encF, align);
  else
    gemm_score_kernel<false><<<dim3(TK_ / SBN, TQ_ / SBM, B_), 256, 0, stream>>>(
        dec2h, dec2l, enc, nullptr, align);

  // 4) softmax rows in place (+ f16 copy if room)
  if (full)
    softmax_kernel<true><<<B_ * TQ_, 256, 0, stream>>>(align, p16);
  else
    softmax_kernel<false><<<B_ * TQ_, 256, 0, stream>>>(align, nullptr);

  // 5) ctx = P @ encT^T (f16), 1-D grid with XCD chunk swizzle
  if (full)
    gemm_ctx_kernel<true><<<dim3((TQ_ / CBM) * (D_ / CBN) * B_), 512, 0, stream>>>(
        align, p16, encT, ctx);
  else
    gemm_ctx_kernel<false><<<dim3((TQ_ / CBM) * (D_ / CBN) * B_), 512, 0, stream>>>(
        align, nullptr, encT, ctx);
}